// Round 15
// baseline (763.554 us; speedup 1.0000x reference)
//
#include <hip/hip_runtime.h>
#include <hip/hip_bf16.h>
#include <cstddef>

// R15: fused 3-layer LSTM, swapped-operand MFMA, PRODUCER-CONSUMER FLAG SYNC
// (no per-step s_barrier). 13 waves / 832 threads, 16 batches/block, grid 256.
//   G0 = w0-2:  L0 tiles {0-4},{5-8},{9-12}; w2 also stages x
//   G1 = w3-7:  L1 tiles {0-2},{3-5},{6-8},{9-10},{11-12}
//   G2 = w8-12: L2 same tiling
// Sync: per-wave monotonic progress words in LDS (prog[group][wave] = last
// completed t), release = lgkmcnt(0) before write; consumers spin on group
// minima (acquire via asm memory clobber + sched_barrier). Wait conditions
// (from 4-deep buffer lifetimes; acyclic -> deadlock-free):
//   L0(t): m0 >= t-1, m1 >= t-4
//   L1(t): m0 >= t,   m1 >= t-1, m2 >= t-4
//   L2(t): m1 >= t,   m2 >= t-1
// Buffers (4 slots, granule = 8k x 16b = 128 shorts, lane-linear reads):
//   H0[4][1024]: L0 act {x@k0-7, h0@k8-57, bias@58}; step t reads slot t&3,
//     writes h0(t) -> slot (t+1)&3; x(t+1) staged -> slot (t+1)&3 g0.
//   H1[4][2048]: L1 act {x=h0@k0-49, h1@k50-99, bias@100}; L0 writes x-part
//     of slot t&3 at its step t; L1 reads slot t&3, writes h-part (t+1)&3.
//   H2[4][2048]: same for L2; L1 writes x-part of slot t&3 at its step t.
// Numerics: 2-term weight split (hi,lo), acts RNE bf16, pre-scaled gates
// (i,f,o x -log2e; g x 2log2e), 8-trans fused cell update. (= R14)

#define T_STEPS 256
#define BTOT    4096
#define NTHR    832

typedef __attribute__((ext_vector_type(8))) short short8;
typedef __attribute__((ext_vector_type(4))) float f32x4;

__device__ __forceinline__ unsigned short f2bf(float x) {     // RNE
    union { __hip_bfloat16 b; unsigned short s; } u;
    u.b = __float2bfloat16(x);
    return u.s;
}
__device__ __forceinline__ float bf2f(unsigned short s) {
    union { unsigned u; float f; } v; v.u = (unsigned)s << 16; return v.f;
}

// Pre-scaled 8-trans cell update (R14): inputs are exp2 args directly.
__device__ __forceinline__ float cell_upd(f32x4 g, float& cst) {
    const float K2 = 2.8853900817779268f;
    float eg  = __builtin_amdgcn_exp2f(fminf(fmaxf(g[2], -126.0f), 126.0f));
    float ei  = __builtin_amdgcn_exp2f(g[0]);
    float ef  = __builtin_amdgcn_exp2f(g[1]);
    float eo  = __builtin_amdgcn_exp2f(g[3]);
    float itg = (eg - 1.0f) * __builtin_amdgcn_rcpf((1.0f + ei) * (1.0f + eg));
    float fg  = __builtin_amdgcn_rcpf(1.0f + ef);
    float c   = fmaf(fg, cst, itg);
    cst = c;
    float ec  = __builtin_amdgcn_exp2f(fminf(fmaxf(K2 * c, -126.0f), 126.0f));
    return (ec - 1.0f) * __builtin_amdgcn_rcpf((1.0f + eo) * (1.0f + ec));
}

// Weights -> (hi,lo) frags, pre-scaled per gate row. (= R14)
template<int NT, int KS, int XK, int BIASK>
__device__ __forceinline__ void load_wb(int T0, int lane,
    const float* __restrict__ w_ih, const float* __restrict__ w_hh,
    const float* __restrict__ b_ih, const float* __restrict__ b_hh,
    short8 (&Wh)[NT][KS], short8 (&Wl)[NT][KS])
{
    const float K1 = 1.4426950408889634f, K2 = 2.8853900817779268f;
    const int m = lane & 15, kg = lane >> 4;
    #pragma unroll
    for (int q = 0; q < NT; ++q) {
        int gp = (T0 + q) * 16 + m;
        int gr = (gp < 200) ? ((gp & 3) * 50 + (gp >> 2)) : -1;
        float scale = ((gp & 3) == 2) ? K2 : -K1;
        #pragma unroll
        for (int ks = 0; ks < KS; ++ks)
            #pragma unroll
            for (int e = 0; e < 8; ++e) {
                int k = ks * 32 + kg * 8 + e;
                float v = 0.0f;
                if (gr >= 0) {
                    if (k < XK) v = w_ih[gr * XK + k];
                    else if (k < XK + 50) v = w_hh[gr * 50 + (k - XK)];
                    else if (k == BIASK) v = b_ih[gr] + b_hh[gr];
                }
                v *= scale;
                unsigned short hb = f2bf(v);
                Wh[q][ks][e] = (short)hb;
                Wl[q][ks][e] = (short)f2bf(v - bf2f(hb));
            }
    }
}

// Spin until group minima reach the needed step counts. CN = word count per
// group (0 = skip). Safety cap -> proceeds (wrong data beats a hang).
template<int C0, int C1, int C2>
__device__ __forceinline__ void spin_wait(volatile int* prog, int n0, int n1, int n2) {
    for (int k = 0; k < 4000000; ++k) {
        bool ok = true;
        if (C0 > 0) {
            int m = prog[0];
            #pragma unroll
            for (int i = 1; i < (C0 > 0 ? C0 : 1); ++i) m = min(m, prog[i]);
            ok &= (m >= n0);
        }
        if (C1 > 0) {
            int m = prog[8];
            #pragma unroll
            for (int i = 1; i < (C1 > 0 ? C1 : 1); ++i) m = min(m, prog[8 + i]);
            ok &= (m >= n1);
        }
        if (C2 > 0) {
            int m = prog[16];
            #pragma unroll
            for (int i = 1; i < (C2 > 0 ? C2 : 1); ++i) m = min(m, prog[16 + i]);
            ok &= (m >= n2);
        }
        if (ok) break;
        __builtin_amdgcn_s_sleep(1);
    }
    asm volatile("" ::: "memory");            // acquire: no data reads above
    __builtin_amdgcn_sched_barrier(0);
}

__device__ __forceinline__ void release_fence() {
    asm volatile("s_waitcnt lgkmcnt(0)" ::: "memory");
    __builtin_amdgcn_sched_barrier(0);
}

// L0 wave: NT tiles, reads H0[t&3], writes h0(t) -> H0[(t+1)&3] (k=8+n) and
// boundary copy -> H1[t&3] (k=n). XST: stages x(t+1) -> H0[(t+1)&3].g0.
template<int T0, int NT, bool XST>
__device__ void role_l0(int lane, int b0, const float* __restrict__ xf,
    const float* w_ih, const float* w_hh, const float* b_ih, const float* b_hh,
    short (*H0)[1024], short (*H1)[2048], volatile int* prog, int pidx)
{
    short8 Wh[NT][2], Wl[NT][2];
    load_wb<NT, 2, 8, 58>(T0, lane, w_ih, w_hh, b_ih, b_hh, Wh, Wl);
    float cst[NT];
    #pragma unroll
    for (int q = 0; q < NT; ++q) cst[q] = 0.0f;
    const int b = lane & 15, kg = lane >> 4;

    for (int t = 0; t < T_STEPS; ++t) {
        const bool stg = XST && (kg == 0) && (t + 1 < T_STEPS);
        float xs[8];
        if (stg) {                            // issue global loads pre-spin
            const float* xr = &xf[((size_t)(b0 + b) * T_STEPS + (t + 1)) * 8];
            *(float4*)&xs[0] = *(const float4*)xr;
            *(float4*)&xs[4] = *(const float4*)(xr + 4);
        }
        spin_wait<3, 5, 0>(prog, t - 1, t - 4, 0);

        const short* rb = H0[t & 3];
        short*       wb = H0[(t + 1) & 3];
        short*       xb = H1[t & 3];

        short8 A0 = *(const short8*)&rb[kg * 128 + b * 8];
        short8 A1 = *(const short8*)&rb[(4 + kg) * 128 + b * 8];

        f32x4 acc[NT];
        #pragma unroll
        for (int q = 0; q < NT; ++q) acc[q] = (f32x4){0.0f, 0.0f, 0.0f, 0.0f};
        #pragma unroll
        for (int q = 0; q < NT; ++q)
            acc[q] = __builtin_amdgcn_mfma_f32_16x16x32_bf16(Wh[q][0], A0, acc[q], 0, 0, 0);
        #pragma unroll
        for (int q = 0; q < NT; ++q)
            acc[q] = __builtin_amdgcn_mfma_f32_16x16x32_bf16(Wh[q][1], A1, acc[q], 0, 0, 0);
        #pragma unroll
        for (int q = 0; q < NT; ++q)
            acc[q] = __builtin_amdgcn_mfma_f32_16x16x32_bf16(Wl[q][0], A0, acc[q], 0, 0, 0);
        #pragma unroll
        for (int q = 0; q < NT; ++q)
            acc[q] = __builtin_amdgcn_mfma_f32_16x16x32_bf16(Wl[q][1], A1, acc[q], 0, 0, 0);

        #pragma unroll
        for (int q = 0; q < NT; ++q) {
            int n = (T0 + q) * 4 + kg;
            if (n < 50) {
                float h = cell_upd(acc[q], cst[q]);
                unsigned short hb = f2bf(h);
                int k = 8 + n;
                wb[(k >> 3) * 128 + b * 8 + (k & 7)] = (short)hb;
                xb[(n >> 3) * 128 + b * 8 + (n & 7)] = (short)hb;
            }
        }
        if (stg) {
            short8 hi;
            #pragma unroll
            for (int e = 0; e < 8; ++e) hi[e] = (short)f2bf(xs[e]);
            *(short8*)&H0[(t + 1) & 3][b * 8] = hi;
        }
        release_fence();
        if (lane == 0) prog[pidx] = t;
    }
}

// Mid wave: NT tiles. L1 (!LASTL): reads H1[t&3], writes h-part H1[(t+1)&3]
// + x-copy H2[t&3]. L2 (LASTL): reads H2[t&3], writes h-part H2[(t+1)&3],
// hf at t=255.
template<int T0, int NT, bool LASTL>
__device__ void role_mid(int lane,
    const float* w_ih, const float* w_hh, const float* b_ih, const float* b_hh,
    short (*H1)[2048], short (*H2)[2048], float* hfp,
    volatile int* prog, int pidx)
{
    short8 Wh[NT][4], Wl[NT][4];
    load_wb<NT, 4, 50, 100>(T0, lane, w_ih, w_hh, b_ih, b_hh, Wh, Wl);
    float cst[NT];
    #pragma unroll
    for (int q = 0; q < NT; ++q) cst[q] = 0.0f;
    const int b = lane & 15, kg = lane >> 4;

    for (int t = 0; t < T_STEPS; ++t) {
        if (LASTL) spin_wait<0, 5, 5>(prog, 0, t, t - 1);
        else       spin_wait<3, 5, 5>(prog, t, t - 1, t - 4);

        const short* rb = LASTL ? H2[t & 3] : H1[t & 3];
        short*       wb = (LASTL ? H2 : H1)[(t + 1) & 3];
        short*       xb = LASTL ? (short*)nullptr : H2[t & 3];

        short8 Ah[4];
        #pragma unroll
        for (int ks = 0; ks < 4; ++ks)
            Ah[ks] = *(const short8*)&rb[(ks * 4 + kg) * 128 + b * 8];

        f32x4 acc[NT];
        #pragma unroll
        for (int q = 0; q < NT; ++q) acc[q] = (f32x4){0.0f, 0.0f, 0.0f, 0.0f};
        #pragma unroll
        for (int ks = 0; ks < 4; ++ks)
            #pragma unroll
            for (int q = 0; q < NT; ++q)
                acc[q] = __builtin_amdgcn_mfma_f32_16x16x32_bf16(Wh[q][ks], Ah[ks], acc[q], 0, 0, 0);
        #pragma unroll
        for (int ks = 0; ks < 4; ++ks)
            #pragma unroll
            for (int q = 0; q < NT; ++q)
                acc[q] = __builtin_amdgcn_mfma_f32_16x16x32_bf16(Wl[q][ks], Ah[ks], acc[q], 0, 0, 0);

        #pragma unroll
        for (int q = 0; q < NT; ++q) {
            int n = (T0 + q) * 4 + kg;
            if (n < 50) {
                float h = cell_upd(acc[q], cst[q]);
                unsigned short hb = f2bf(h);
                int k = 50 + n;
                wb[(k >> 3) * 128 + b * 8 + (k & 7)] = (short)hb;
                if (!LASTL)
                    xb[(n >> 3) * 128 + b * 8 + (n & 7)] = (short)hb;
                if (LASTL && t == T_STEPS - 1) hfp[b * 56 + n] = h;
            }
        }
        release_fence();
        if (lane == 0) prog[pidx] = t;
    }
}

__global__ __launch_bounds__(NTHR) void lstm_fused(
    const float* __restrict__ xf,
    const float* w_ih0, const float* w_hh0, const float* b_ih0, const float* b_hh0,
    const float* w_ih1, const float* w_hh1, const float* b_ih1, const float* b_hh1,
    const float* w_ih2, const float* w_hh2, const float* b_ih2, const float* b_hh2,
    const float* __restrict__ w_fc, const float* __restrict__ b_fc,
    float* __restrict__ out)
{
    __shared__ __align__(16) short H0[4][1024];
    __shared__ __align__(16) short H1[4][2048];
    __shared__ __align__(16) short H2[4][2048];
    __shared__ __align__(16) float hf[16 * 56];
    __shared__ int prog[24];   // [0..7] G0 (3 used), [8..15] G1 (5), [16..23] G2 (5)

    const int tid  = threadIdx.x;
    const int lane = tid & 63;
    const int wid  = tid >> 6;
    const int b0   = blockIdx.x * 16;

    for (int i = tid; i < 4096; i += NTHR) ((short*)H0)[i] = 0;
    for (int i = tid; i < 8192; i += NTHR) { ((short*)H1)[i] = 0; ((short*)H2)[i] = 0; }
    if (tid < 24) {
        bool used = (tid < 3) || (tid >= 8 && tid < 13) || (tid >= 16 && tid < 21);
        prog[tid] = used ? -1 : 0x7FFFFFFF;
    }
    __syncthreads();

    // bias act columns = 1.0 in all 4 slots (L0 k=58; L1/L2 k=100); x(0)
    if (tid < 64) {
        int slot = tid >> 4, b = tid & 15;
        H0[slot][(58 >> 3) * 128 + b * 8 + (58 & 7)]   = (short)0x3F80;
        H1[slot][(100 >> 3) * 128 + b * 8 + (100 & 7)] = (short)0x3F80;
        H2[slot][(100 >> 3) * 128 + b * 8 + (100 & 7)] = (short)0x3F80;
    }
    if (tid < 16) {
        int b = tid;
        #pragma unroll
        for (int j = 0; j < 8; ++j) {
            float v = xf[((size_t)(b0 + b) * T_STEPS + 0) * 8 + j];
            H0[0][b * 8 + j] = (short)f2bf(v);
        }
    }
    __syncthreads();

    volatile int* pg = prog;
    if      (wid == 0)  role_l0<0, 5, false>(lane, b0, xf, w_ih0, w_hh0, b_ih0, b_hh0, H0, H1, pg, 0);
    else if (wid == 1)  role_l0<5, 4, false>(lane, b0, xf, w_ih0, w_hh0, b_ih0, b_hh0, H0, H1, pg, 1);
    else if (wid == 2)  role_l0<9, 4, true >(lane, b0, xf, w_ih0, w_hh0, b_ih0, b_hh0, H0, H1, pg, 2);
    else if (wid == 3)  role_mid<0,  3, false>(lane, w_ih1, w_hh1, b_ih1, b_hh1, H1, H2, nullptr, pg, 8);
    else if (wid == 4)  role_mid<3,  3, false>(lane, w_ih1, w_hh1, b_ih1, b_hh1, H1, H2, nullptr, pg, 9);
    else if (wid == 5)  role_mid<6,  3, false>(lane, w_ih1, w_hh1, b_ih1, b_hh1, H1, H2, nullptr, pg, 10);
    else if (wid == 6)  role_mid<9,  2, false>(lane, w_ih1, w_hh1, b_ih1, b_hh1, H1, H2, nullptr, pg, 11);
    else if (wid == 7)  role_mid<11, 2, false>(lane, w_ih1, w_hh1, b_ih1, b_hh1, H1, H2, nullptr, pg, 12);
    else if (wid == 8)  role_mid<0,  3, true >(lane, w_ih2, w_hh2, b_ih2, b_hh2, H1, H2, hf, pg, 16);
    else if (wid == 9)  role_mid<3,  3, true >(lane, w_ih2, w_hh2, b_ih2, b_hh2, H1, H2, hf, pg, 17);
    else if (wid == 10) role_mid<6,  3, true >(lane, w_ih2, w_hh2, b_ih2, b_hh2, H1, H2, hf, pg, 18);
    else if (wid == 11) role_mid<9,  2, true >(lane, w_ih2, w_hh2, b_ih2, b_hh2, H1, H2, hf, pg, 19);
    else                role_mid<11, 2, true >(lane, w_ih2, w_hh2, b_ih2, b_hh2, H1, H2, hf, pg, 20);

    __syncthreads();

    if (tid < 96) {
        int b = tid / 6, o = tid - b * 6;
        float a = b_fc[o];
        #pragma unroll
        for (int n = 0; n < 50; ++n)
            a = fmaf(w_fc[o * 50 + n], hf[b * 56 + n], a);
        out[(size_t)(b0 + b) * 6 + o] = a;
    }
}

extern "C" void kernel_launch(void* const* d_in, const int* in_sizes, int n_in,
                              void* d_out, int out_size, void* d_ws, size_t ws_size,
                              hipStream_t stream) {
    (void)in_sizes; (void)n_in; (void)d_ws; (void)ws_size; (void)out_size;

    const float* x     = (const float*)d_in[0];
    const float* w_ih0 = (const float*)d_in[1];
    const float* w_hh0 = (const float*)d_in[2];
    const float* b_ih0 = (const float*)d_in[3];
    const float* b_hh0 = (const float*)d_in[4];
    const float* w_ih1 = (const float*)d_in[5];
    const float* w_hh1 = (const float*)d_in[6];
    const float* b_ih1 = (const float*)d_in[7];
    const float* b_hh1 = (const float*)d_in[8];
    const float* w_ih2 = (const float*)d_in[9];
    const float* w_hh2 = (const float*)d_in[10];
    const float* b_ih2 = (const float*)d_in[11];
    const float* b_hh2 = (const float*)d_in[12];
    const float* w_fc  = (const float*)d_in[13];
    const float* b_fc  = (const float*)d_in[14];
    float* out = (float*)d_out;

    lstm_fused<<<dim3(BTOT / 16), dim3(NTHR), 0, stream>>>(
        x, w_ih0, w_hh0, b_ih0, b_hh0, w_ih1, w_hh1, b_ih1, b_hh1,
        w_ih2, w_hh2, b_ih2, b_hh2, w_fc, b_fc, out);
}

// Round 16
// 265.226 us; speedup vs baseline: 2.8789x; 2.8789x over previous
//
#include <hip/hip_runtime.h>
#include <hip/hip_bf16.h>
#include <cstddef>

// R16 = R14 structure (best, 303us), precision swapped bf16->fp16:
//  - fp16 has 2^-11 rel precision -> SINGLE-term weights suffice (the bf16
//    hi/lo split is deleted): MFMA count halves (260->130/block-iter),
//    chain depth halves, W-frag VGPRs halve.
//  - acts stored fp16: quantization improves 2^-9 -> 2^-11 (absmax should DROP).
//  - range safe: |pre-scaled gates| <= ~40 << 65504; weights ~0.2 max.
// Structure (R9/R14): 12 waves, 768 thr, w0-2 L0 {0-4},{5-8},{9-12}(+x),
// w3-6 L1 NT=3, w7-10 L2 NT=3, w11 dual-orphan (L1+L2 tile12).
// Skew: L0@it, L1@it-1, L2@it-2. ONE s_barrier/iter.
// Act LDS fragment-major: addr(k,b)=(k>>3)*128+b*8+(k&7) shorts.
// Bias rides act==1.0 column (fp16 0x3C00): L0 k=58, L1/L2 k=100.
// Gates pre-scaled at load (i,f,o x -log2e; g x 2log2e); 8-trans update.

#define T_STEPS 256
#define BTOT    4096
#define NTHR    768

typedef __attribute__((ext_vector_type(8))) _Float16 half8;
typedef __attribute__((ext_vector_type(4))) float    f32x4;

#define BAR() do { \
    asm volatile("s_waitcnt lgkmcnt(0)" ::: "memory"); \
    __builtin_amdgcn_sched_barrier(0); \
    __builtin_amdgcn_s_barrier(); \
    __builtin_amdgcn_sched_barrier(0); \
} while (0)

__device__ __forceinline__ unsigned short f2h(float x) {
    union { _Float16 h; unsigned short s; } u;
    u.h = (_Float16)x;
    return u.s;
}

// Pre-scaled 8-trans cell update: inputs are exp2 args directly.
__device__ __forceinline__ float cell_upd(f32x4 g, float& cst) {
    const float K2 = 2.8853900817779268f;
    float eg  = __builtin_amdgcn_exp2f(fminf(fmaxf(g[2], -126.0f), 126.0f));
    float ei  = __builtin_amdgcn_exp2f(g[0]);
    float ef  = __builtin_amdgcn_exp2f(g[1]);
    float eo  = __builtin_amdgcn_exp2f(g[3]);
    float itg = (eg - 1.0f) * __builtin_amdgcn_rcpf((1.0f + ei) * (1.0f + eg));
    float fg  = __builtin_amdgcn_rcpf(1.0f + ef);
    float c   = fmaf(fg, cst, itg);
    cst = c;
    float ec  = __builtin_amdgcn_exp2f(fminf(fmaxf(K2 * c, -126.0f), 126.0f));
    return (ec - 1.0f) * __builtin_amdgcn_rcpf((1.0f + eo) * (1.0f + ec));
}

// Weights -> fp16 frags (single term), pre-scaled per gate row: rows with
// (gp&3)==2 (tanh gate) by +K2, others by -K1. Bias scales identically.
// K-packed [w_ih(XK) | w_hh(50) | bias@BIASK]. Row N' = (T0+q)*16+(lane&15),
// k = ks*32 + (lane>>4)*8 + e.
template<int NT, int KS, int XK, int BIASK>
__device__ __forceinline__ void load_wb(int T0, int lane,
    const float* __restrict__ w_ih, const float* __restrict__ w_hh,
    const float* __restrict__ b_ih, const float* __restrict__ b_hh,
    half8 (&W)[NT][KS])
{
    const float K1 = 1.4426950408889634f, K2 = 2.8853900817779268f;
    const int m = lane & 15, kg = lane >> 4;
    #pragma unroll
    for (int q = 0; q < NT; ++q) {
        int gp = (T0 + q) * 16 + m;
        int gr = (gp < 200) ? ((gp & 3) * 50 + (gp >> 2)) : -1;
        float scale = ((gp & 3) == 2) ? K2 : -K1;
        #pragma unroll
        for (int ks = 0; ks < KS; ++ks)
            #pragma unroll
            for (int e = 0; e < 8; ++e) {
                int k = ks * 32 + kg * 8 + e;
                float v = 0.0f;
                if (gr >= 0) {
                    if (k < XK) v = w_ih[gr * XK + k];
                    else if (k < XK + 50) v = w_hh[gr * 50 + (k - XK)];
                    else if (k == BIASK) v = b_ih[gr] + b_hh[gr];
                }
                W[q][ks][e] = (_Float16)(v * scale);
            }
    }
}

// One layer-step: batched A-frag reads, fp16 MFMA (ks-parity dual acc for
// latency), in-register cell update, fp16 h write.
template<int NT, int KS, int HK, bool WRB, bool LASTL>
__device__ __forceinline__ void step_body(
    int t, int T0, int lane,
    const short* Arh, short* Awh, short* Axh, float* hfp,
    const half8 (&W)[NT][KS], float (&cst)[NT])
{
    const int b = lane & 15, kg = lane >> 4;

    half8 Ah[KS];
    #pragma unroll
    for (int ks = 0; ks < KS; ++ks)
        Ah[ks] = *(const half8*)&Arh[(ks * 4 + kg) * 128 + b * 8];

    f32x4 accA[NT], accB[NT];
    #pragma unroll
    for (int q = 0; q < NT; ++q) {
        accA[q] = (f32x4){0.0f, 0.0f, 0.0f, 0.0f};
        accB[q] = (f32x4){0.0f, 0.0f, 0.0f, 0.0f};
    }
    #pragma unroll
    for (int ks = 0; ks < KS; ++ks) {
        if ((ks & 1) == 0) {
            #pragma unroll
            for (int q = 0; q < NT; ++q)
                accA[q] = __builtin_amdgcn_mfma_f32_16x16x32_f16(W[q][ks], Ah[ks], accA[q], 0, 0, 0);
        } else {
            #pragma unroll
            for (int q = 0; q < NT; ++q)
                accB[q] = __builtin_amdgcn_mfma_f32_16x16x32_f16(W[q][ks], Ah[ks], accB[q], 0, 0, 0);
        }
    }

    #pragma unroll
    for (int q = 0; q < NT; ++q) {
        int n = (T0 + q) * 4 + kg;
        if (n < 50) {
            float h = cell_upd(accA[q] + accB[q], cst[q]);
            unsigned short hb = f2h(h);
            int k = HK + n;
            Awh[(k >> 3) * 128 + b * 8 + (k & 7)] = (short)hb;
            if (WRB)
                Axh[(n >> 3) * 128 + b * 8 + (n & 7)] = (short)hb;
            if (LASTL && t == T_STEPS - 1) hfp[b * 56 + n] = h;
        }
    }
}

template<int NT, bool XST>
__device__ void role_l0(int T0, int lane, int b0, const float* __restrict__ xf,
    const float* w_ih, const float* w_hh, const float* b_ih, const float* b_hh,
    short (*A0h)[1024], short (*A1h)[2048])
{
    half8 W[NT][2];
    load_wb<NT, 2, 8, 58>(T0, lane, w_ih, w_hh, b_ih, b_hh, W);
    float cst[NT];
    #pragma unroll
    for (int q = 0; q < NT; ++q) cst[q] = 0.0f;
    const int bb = lane & 15, kg = lane >> 4;

    for (int it = 0; it < T_STEPS + 2; ++it) {
        const bool stg = XST && (kg == 0) && (it + 1 < T_STEPS);
        float xs[8];
        if (stg) {
            const float* xr = &xf[((size_t)(b0 + bb) * T_STEPS + (it + 1)) * 8];
            *(float4*)&xs[0] = *(const float4*)xr;
            *(float4*)&xs[4] = *(const float4*)(xr + 4);
        }
        if (it < T_STEPS) {
            int cur = it & 1, nxt = cur ^ 1;
            step_body<NT, 2, 8, true, false>(it, T0, lane,
                A0h[cur], A0h[nxt], A1h[cur], nullptr, W, cst);
        }
        if (stg) {
            short hi[8];
            #pragma unroll
            for (int e = 0; e < 8; ++e) hi[e] = (short)f2h(xs[e]);
            *(half8*)&A0h[(it + 1) & 1][bb * 8] = *(half8*)hi;
        }
        BAR();
    }
}

// Mid-layer wave, NT=3. LASTL: L2 (skew 2, hf at t=255); else L1 (-> A2).
template<bool LASTL>
__device__ void role_mid(int T0, int lane,
    const float* w_ih, const float* w_hh, const float* b_ih, const float* b_hh,
    short (*Arh)[2048], short (*Axh)[2048], float* hfp)
{
    constexpr int SKEW = LASTL ? 2 : 1;
    half8 W[3][4];
    load_wb<3, 4, 50, 100>(T0, lane, w_ih, w_hh, b_ih, b_hh, W);
    float cst[3] = {0.0f, 0.0f, 0.0f};

    for (int it = 0; it < T_STEPS + 2; ++it) {
        int t = it - SKEW;
        if (t >= 0 && t < T_STEPS) {
            step_body<3, 4, 50, !LASTL, LASTL>(t, T0, lane,
                Arh[t & 1], Arh[(t + 1) & 1],
                LASTL ? (short*)nullptr : Axh[t & 1],
                hfp, W, cst);
        }
        BAR();
    }
}

// Fused dual-orphan: L1 tile12 (t1=it-1) + L2 tile12 (t2=it-2).
__device__ void role_orphan(int lane,
    const float* w_ih1, const float* w_hh1, const float* b_ih1, const float* b_hh1,
    const float* w_ih2, const float* w_hh2, const float* b_ih2, const float* b_hh2,
    short (*A1h)[2048], short (*A2h)[2048], float* hfp)
{
    half8 W1[1][4], W2[1][4];
    load_wb<1, 4, 50, 100>(12, lane, w_ih1, w_hh1, b_ih1, b_hh1, W1);
    load_wb<1, 4, 50, 100>(12, lane, w_ih2, w_hh2, b_ih2, b_hh2, W2);
    float c1 = 0.0f, c2 = 0.0f;
    const int b = lane & 15, kg = lane >> 4;

    for (int it = 0; it < T_STEPS + 2; ++it) {
        int t1 = it - 1, t2 = it - 2;
        bool d1 = (unsigned)t1 < T_STEPS, d2 = (unsigned)t2 < T_STEPS;

        half8 A1[4], A2[4];
        #pragma unroll
        for (int ks = 0; ks < 4; ++ks) {
            int ga = (ks * 4 + kg) * 128 + b * 8;
            if (d1) A1[ks] = *(const half8*)&A1h[t1 & 1][ga];
            if (d2) A2[ks] = *(const half8*)&A2h[t2 & 1][ga];
        }

        f32x4 a1 = (f32x4){0.0f, 0.0f, 0.0f, 0.0f};
        f32x4 a2 = (f32x4){0.0f, 0.0f, 0.0f, 0.0f};
        #pragma unroll
        for (int ks = 0; ks < 4; ++ks) {
            if (d1) a1 = __builtin_amdgcn_mfma_f32_16x16x32_f16(W1[0][ks], A1[ks], a1, 0, 0, 0);
            if (d2) a2 = __builtin_amdgcn_mfma_f32_16x16x32_f16(W2[0][ks], A2[ks], a2, 0, 0, 0);
        }

        const int n = 48 + kg;                     // valid kg<2
        if (d1 && kg < 2) {
            float h = cell_upd(a1, c1);
            unsigned short hb = f2h(h);
            int k = 50 + n;
            A1h[(t1 + 1) & 1][(k >> 3) * 128 + b * 8 + (k & 7)] = (short)hb;
            A2h[t1 & 1][(n >> 3) * 128 + b * 8 + (n & 7)] = (short)hb;
        }
        if (d2 && kg < 2) {
            float h = cell_upd(a2, c2);
            unsigned short hb = f2h(h);
            int k = 50 + n;
            A2h[(t2 + 1) & 1][(k >> 3) * 128 + b * 8 + (k & 7)] = (short)hb;
            if (t2 == T_STEPS - 1) hfp[b * 56 + n] = h;
        }
        BAR();
    }
}

__global__ __launch_bounds__(NTHR) void lstm_fused(
    const float* __restrict__ xf,
    const float* w_ih0, const float* w_hh0, const float* b_ih0, const float* b_hh0,
    const float* w_ih1, const float* w_hh1, const float* b_ih1, const float* b_hh1,
    const float* w_ih2, const float* w_hh2, const float* b_ih2, const float* b_hh2,
    const float* __restrict__ w_fc, const float* __restrict__ b_fc,
    float* __restrict__ out)
{
    __shared__ __align__(16) short A0h[2][1024];   // L0 act (K=64), fp16
    __shared__ __align__(16) short A1h[2][2048];   // L1 act (K=128)
    __shared__ __align__(16) short A2h[2][2048];   // L2 act (K=128)
    __shared__ __align__(16) float hf[16 * 56];

    const int tid  = threadIdx.x;
    const int lane = tid & 63;
    const int wid  = tid >> 6;
    const int b0   = blockIdx.x * 16;

    for (int i = tid; i < 2048; i += NTHR) ((short*)A0h)[i] = 0;
    for (int i = tid; i < 4096; i += NTHR) { ((short*)A1h)[i] = 0; ((short*)A2h)[i] = 0; }
    __syncthreads();

    // bias act columns = 1.0 fp16 (0x3C00); x(0) -> A0 buf0
    if (tid < 32) {
        int buf = tid >> 4, b = tid & 15;
        A0h[buf][(58 >> 3) * 128 + b * 8 + (58 & 7)]   = (short)0x3C00;
        A1h[buf][(100 >> 3) * 128 + b * 8 + (100 & 7)] = (short)0x3C00;
        A2h[buf][(100 >> 3) * 128 + b * 8 + (100 & 7)] = (short)0x3C00;
    }
    if (tid < 16) {
        int b = tid;
        #pragma unroll
        for (int j = 0; j < 8; ++j) {
            float v = xf[((size_t)(b0 + b) * T_STEPS + 0) * 8 + j];
            A0h[0][b * 8 + j] = (short)f2h(v);
        }
    }
    __syncthreads();

    if      (wid == 0)  role_l0<5, false>(0, lane, b0, xf, w_ih0, w_hh0, b_ih0, b_hh0, A0h, A1h);
    else if (wid == 1)  role_l0<4, false>(5, lane, b0, xf, w_ih0, w_hh0, b_ih0, b_hh0, A0h, A1h);
    else if (wid == 2)  role_l0<4, true >(9, lane, b0, xf, w_ih0, w_hh0, b_ih0, b_hh0, A0h, A1h);
    else if (wid == 3)  role_mid<false>(0, lane, w_ih1, w_hh1, b_ih1, b_hh1, A1h, A2h, nullptr);
    else if (wid == 4)  role_mid<false>(3, lane, w_ih1, w_hh1, b_ih1, b_hh1, A1h, A2h, nullptr);
    else if (wid == 5)  role_mid<false>(6, lane, w_ih1, w_hh1, b_ih1, b_hh1, A1h, A2h, nullptr);
    else if (wid == 6)  role_mid<false>(9, lane, w_ih1, w_hh1, b_ih1, b_hh1, A1h, A2h, nullptr);
    else if (wid == 7)  role_mid<true >(0, lane, w_ih2, w_hh2, b_ih2, b_hh2, A2h, nullptr, hf);
    else if (wid == 8)  role_mid<true >(3, lane, w_ih2, w_hh2, b_ih2, b_hh2, A2h, nullptr, hf);
    else if (wid == 9)  role_mid<true >(6, lane, w_ih2, w_hh2, b_ih2, b_hh2, A2h, nullptr, hf);
    else if (wid == 10) role_mid<true >(9, lane, w_ih2, w_hh2, b_ih2, b_hh2, A2h, nullptr, hf);
    else                role_orphan(lane,
                            w_ih1, w_hh1, b_ih1, b_hh1,
                            w_ih2, w_hh2, b_ih2, b_hh2,
                            A1h, A2h, hf);

    __syncthreads();

    if (tid < 96) {
        int b = tid / 6, o = tid - b * 6;
        float a = b_fc[o];
        #pragma unroll
        for (int n = 0; n < 50; ++n)
            a = fmaf(w_fc[o * 50 + n], hf[b * 56 + n], a);
        out[(size_t)(b0 + b) * 6 + o] = a;
    }
}

extern "C" void kernel_launch(void* const* d_in, const int* in_sizes, int n_in,
                              void* d_out, int out_size, void* d_ws, size_t ws_size,
                              hipStream_t stream) {
    (void)in_sizes; (void)n_in; (void)d_ws; (void)ws_size; (void)out_size;

    const float* x     = (const float*)d_in[0];
    const float* w_ih0 = (const float*)d_in[1];
    const float* w_hh0 = (const float*)d_in[2];
    const float* b_ih0 = (const float*)d_in[3];
    const float* b_hh0 = (const float*)d_in[4];
    const float* w_ih1 = (const float*)d_in[5];
    const float* w_hh1 = (const float*)d_in[6];
    const float* b_ih1 = (const float*)d_in[7];
    const float* b_hh1 = (const float*)d_in[8];
    const float* w_ih2 = (const float*)d_in[9];
    const float* w_hh2 = (const float*)d_in[10];
    const float* b_ih2 = (const float*)d_in[11];
    const float* b_hh2 = (const float*)d_in[12];
    const float* w_fc  = (const float*)d_in[13];
    const float* b_fc  = (const float*)d_in[14];
    float* out = (float*)d_out;

    lstm_fused<<<dim3(BTOT / 16), dim3(NTHR), 0, stream>>>(
        x, w_ih0, w_hh0, b_ih0, b_hh0, w_ih1, w_hh1, b_ih1, b_hh1,
        w_ih2, w_hh2, b_ih2, b_hh2, w_fc, b_fc, out);
}

// Round 17
// 256.421 us; speedup vs baseline: 2.9777x; 1.0343x over previous
//
#include <hip/hip_runtime.h>
#include <hip/hip_bf16.h>
#include <cstddef>

// R17 = R16 (fp16 single-term, 12 waves, 265us) + granule-shared h regions
// (R11's verified single-write scheme): each layer writes h ONCE into its own
// region; consumer layer reads the SAME region at +1 granule shift. Boundary
// double-writes deleted. Cell update byte-identical to R16.
//
// Regions (granule = 8k x 16b = 128 shorts; 9 granules = 1152 shorts/buf):
//   H0[2], H1[3], H2[2].  g0 = x (L0 only); g1..g7 = h units 0..55
//   (unit u -> granule 1+(u>>3), pos u&7); act==1.0 bias column at g7p2
//   (= unit slot 50); g8 = zero pad (read by shifted consumers only).
// Weight k-maps:  L0: [w_ih@k0-7 | w_hh@k8-57 | bias@58]   (reads g0..7)
//   MID: [w_ih@k0-49 | bias@50 | 0 | w_hh@k64-113 | 0]     (x-side reads
//   producer region g1..8; h-side reads own region g1..8)
// Schedule (skews L0@it, L1@it-1, L2@it-2; ONE s_barrier/iter):
//   h0(t)->H0[(t+1)&1]; x(t+1) staged -> H0[(t+1)&1].g0
//   h1(t)->H1[t%3]; L1@it: x-side H0[it&1], h-side H1[(it-2)%3], write H1[(it-1)%3]
//   h2(t)->H2[t&1]; L2@it: x-side H1[(it-2)%3], h-side H2[(it+1)&1], write H2[it&1]
// Roles: w0-2 L0 {0-4},{5-8},{9-12}(+x-stage on w2); w3-6 L1 NT=3;
// w7-10 L2 NT=3; w11 dual-orphan (L1+L2 tile12).
// Numerics: fp16 weights/acts, pre-scaled gates (i,f,o x -log2e; g x 2log2e),
// 8-trans fused update (= R16).

#define T_STEPS 256
#define NITER   258
#define BTOT    4096
#define NTHR    768
#define GS      128
#define BUFR    1152        // 9 granules

typedef __attribute__((ext_vector_type(8))) _Float16 half8;
typedef __attribute__((ext_vector_type(4))) float    f32x4;

#define BAR() do { \
    asm volatile("s_waitcnt lgkmcnt(0)" ::: "memory"); \
    __builtin_amdgcn_sched_barrier(0); \
    __builtin_amdgcn_s_barrier(); \
    __builtin_amdgcn_sched_barrier(0); \
} while (0)

__device__ __forceinline__ unsigned short f2h(float x) {
    union { _Float16 h; unsigned short s; } u;
    u.h = (_Float16)x;
    return u.s;
}

// Pre-scaled 8-trans cell update (= R16).
__device__ __forceinline__ float cell_upd(f32x4 g, float& cst) {
    const float K2 = 2.8853900817779268f;
    float eg  = __builtin_amdgcn_exp2f(fminf(fmaxf(g[2], -126.0f), 126.0f));
    float ei  = __builtin_amdgcn_exp2f(g[0]);
    float ef  = __builtin_amdgcn_exp2f(g[1]);
    float eo  = __builtin_amdgcn_exp2f(g[3]);
    float itg = (eg - 1.0f) * __builtin_amdgcn_rcpf((1.0f + ei) * (1.0f + eg));
    float fg  = __builtin_amdgcn_rcpf(1.0f + ef);
    float c   = fmaf(fg, cst, itg);
    cst = c;
    float ec  = __builtin_amdgcn_exp2f(fminf(fmaxf(K2 * c, -126.0f), 126.0f));
    return (ec - 1.0f) * __builtin_amdgcn_rcpf((1.0f + eo) * (1.0f + ec));
}

// Weights -> fp16 frags, pre-scaled per gate row ((gp&3)==2 -> +K2 else -K1).
// L0M: [w_ih(8)@k0-7 | w_hh@k8-57 | bias@58].
// MID: [w_ih@k0-49 | bias@50 | zeros | w_hh@k64-113 | zeros].
template<bool L0M, int NT, int KS>
__device__ __forceinline__ void load_wb(int T0, int lane,
    const float* __restrict__ w_ih, const float* __restrict__ w_hh,
    const float* __restrict__ b_ih, const float* __restrict__ b_hh,
    half8 (&W)[NT][KS])
{
    const float K1 = 1.4426950408889634f, K2 = 2.8853900817779268f;
    const int m = lane & 15, kg = lane >> 4;
    #pragma unroll
    for (int q = 0; q < NT; ++q) {
        int gp = (T0 + q) * 16 + m;
        int gr = (gp < 200) ? ((gp & 3) * 50 + (gp >> 2)) : -1;
        float scale = ((gp & 3) == 2) ? K2 : -K1;
        #pragma unroll
        for (int ks = 0; ks < KS; ++ks)
            #pragma unroll
            for (int e = 0; e < 8; ++e) {
                int k = ks * 32 + kg * 8 + e;
                float v = 0.0f;
                if (gr >= 0) {
                    if (L0M) {
                        if (k < 8) v = w_ih[gr * 8 + k];
                        else if (k < 58) v = w_hh[gr * 50 + (k - 8)];
                        else if (k == 58) v = b_ih[gr] + b_hh[gr];
                    } else {
                        if (k < 50) v = w_ih[gr * 50 + k];
                        else if (k == 50) v = b_ih[gr] + b_hh[gr];
                        else if (k >= 64 && k < 114) v = w_hh[gr * 50 + (k - 64)];
                    }
                }
                W[q][ks][e] = (_Float16)(v * scale);
            }
    }
}

// L0 wave: reads own region H0[it&1] g0..7 (unshifted); writes h once.
template<int T0, int NT, bool XST>
__device__ void role_l0(int lane, int b0, const float* __restrict__ xf,
    const float* w_ih, const float* w_hh, const float* b_ih, const float* b_hh,
    short (*H0)[BUFR])
{
    half8 W[NT][2];
    load_wb<true, NT, 2>(T0, lane, w_ih, w_hh, b_ih, b_hh, W);
    float cst[NT];
    #pragma unroll
    for (int q = 0; q < NT; ++q) cst[q] = 0.0f;
    const int b = lane & 15, kg = lane >> 4;

    for (int it = 0; it < NITER; ++it) {
        const bool stg = XST && (kg == 0) && (it + 1 < T_STEPS);
        float xs[8];
        if (stg) {
            const float* xr = &xf[((size_t)(b0 + b) * T_STEPS + (it + 1)) * 8];
            *(float4*)&xs[0] = *(const float4*)xr;
            *(float4*)&xs[4] = *(const float4*)(xr + 4);
        }
        if (it < T_STEPS) {
            const short* rb = H0[it & 1];
            short*       wb = H0[(it + 1) & 1];
            half8 A0 = *(const half8*)&rb[kg * GS + b * 8];
            half8 A1 = *(const half8*)&rb[(4 + kg) * GS + b * 8];
            f32x4 accA[NT], accB[NT];
            #pragma unroll
            for (int q = 0; q < NT; ++q) {
                accA[q] = (f32x4){0.0f, 0.0f, 0.0f, 0.0f};
                accB[q] = (f32x4){0.0f, 0.0f, 0.0f, 0.0f};
            }
            #pragma unroll
            for (int q = 0; q < NT; ++q)
                accA[q] = __builtin_amdgcn_mfma_f32_16x16x32_f16(W[q][0], A0, accA[q], 0, 0, 0);
            #pragma unroll
            for (int q = 0; q < NT; ++q)
                accB[q] = __builtin_amdgcn_mfma_f32_16x16x32_f16(W[q][1], A1, accB[q], 0, 0, 0);
            #pragma unroll
            for (int q = 0; q < NT; ++q) {
                int n = (T0 + q) * 4 + kg;
                if (n < 50) {
                    float h = cell_upd(accA[q] + accB[q], cst[q]);
                    wb[(1 + (n >> 3)) * GS + b * 8 + (n & 7)] = (short)f2h(h);
                }
            }
        }
        if (stg) {
            short hi[8];
            #pragma unroll
            for (int e = 0; e < 8; ++e) hi[e] = (short)f2h(xs[e]);
            *(half8*)&H0[(it + 1) & 1][b * 8] = *(half8*)hi;
        }
        BAR();
    }
}

// Mid wave, NT=3. x-side = producer region +1-granule shift; h-side = own
// region +1-granule shift. Single h write. LASTL: L2 (skew 2, hf@t=255).
template<int T0, bool LASTL>
__device__ void role_mid(int lane,
    const float* w_ih, const float* w_hh, const float* b_ih, const float* b_hh,
    short (*H0)[BUFR], short (*H1)[BUFR], short (*H2)[BUFR], float* hfp)
{
    constexpr int SKEW = LASTL ? 2 : 1;
    half8 W[3][4];
    load_wb<false, 3, 4>(T0, lane, w_ih, w_hh, b_ih, b_hh, W);
    float cst[3] = {0.0f, 0.0f, 0.0f};
    const int b = lane & 15, kg = lane >> 4;
    int m0 = 0, m1 = 2, m2 = 1;     // it%3, (it-1)%3, (it-2)%3

    for (int it = 0; it < NITER; ++it) {
        int t = it - SKEW;
        if ((unsigned)t < T_STEPS) {
            const short* xsb = LASTL ? H1[m2] : H0[it & 1];
            const short* hsb = LASTL ? H2[(it + 1) & 1] : H1[m2];
            short*       wb  = LASTL ? H2[it & 1]       : H1[m1];

            half8 Ap[4];
            Ap[0] = *(const half8*)&xsb[(1 + kg) * GS + b * 8];
            Ap[1] = *(const half8*)&xsb[(5 + kg) * GS + b * 8];
            Ap[2] = *(const half8*)&hsb[(1 + kg) * GS + b * 8];
            Ap[3] = *(const half8*)&hsb[(5 + kg) * GS + b * 8];

            f32x4 accA[3], accB[3];
            #pragma unroll
            for (int q = 0; q < 3; ++q) {
                accA[q] = (f32x4){0.0f, 0.0f, 0.0f, 0.0f};
                accB[q] = (f32x4){0.0f, 0.0f, 0.0f, 0.0f};
            }
            #pragma unroll
            for (int ks = 0; ks < 4; ++ks) {
                if ((ks & 1) == 0) {
                    #pragma unroll
                    for (int q = 0; q < 3; ++q)
                        accA[q] = __builtin_amdgcn_mfma_f32_16x16x32_f16(W[q][ks], Ap[ks], accA[q], 0, 0, 0);
                } else {
                    #pragma unroll
                    for (int q = 0; q < 3; ++q)
                        accB[q] = __builtin_amdgcn_mfma_f32_16x16x32_f16(W[q][ks], Ap[ks], accB[q], 0, 0, 0);
                }
            }

            #pragma unroll
            for (int q = 0; q < 3; ++q) {
                int n = (T0 + q) * 4 + kg;
                if (n < 50) {
                    float h = cell_upd(accA[q] + accB[q], cst[q]);
                    wb[(1 + (n >> 3)) * GS + b * 8 + (n & 7)] = (short)f2h(h);
                    if (LASTL && t == T_STEPS - 1) hfp[b * 56 + n] = h;
                }
            }
        }
        BAR();
        int tmp = m2; m2 = m1; m1 = m0; m0 = tmp;
    }
}

// Dual-orphan: L1 tile12 (t1=it-1) + L2 tile12 (t2=it-2); units 48,49 (kg<2).
__device__ void role_orphan(int lane,
    const float* w_ih1, const float* w_hh1, const float* b_ih1, const float* b_hh1,
    const float* w_ih2, const float* w_hh2, const float* b_ih2, const float* b_hh2,
    short (*H0)[BUFR], short (*H1)[BUFR], short (*H2)[BUFR], float* hfp)
{
    half8 W1[1][4], W2[1][4];
    load_wb<false, 1, 4>(12, lane, w_ih1, w_hh1, b_ih1, b_hh1, W1);
    load_wb<false, 1, 4>(12, lane, w_ih2, w_hh2, b_ih2, b_hh2, W2);
    float c1 = 0.0f, c2 = 0.0f;
    const int b = lane & 15, kg = lane >> 4;
    int m0 = 0, m1 = 2, m2 = 1;

    for (int it = 0; it < NITER; ++it) {
        int t1 = it - 1, t2 = it - 2;
        bool d1 = (unsigned)t1 < T_STEPS, d2 = (unsigned)t2 < T_STEPS;

        half8 A1[4], A2[4];
        if (d1) {
            const short* xsb = H0[it & 1];
            const short* hsb = H1[m2];
            A1[0] = *(const half8*)&xsb[(1 + kg) * GS + b * 8];
            A1[1] = *(const half8*)&xsb[(5 + kg) * GS + b * 8];
            A1[2] = *(const half8*)&hsb[(1 + kg) * GS + b * 8];
            A1[3] = *(const half8*)&hsb[(5 + kg) * GS + b * 8];
        }
        if (d2) {
            const short* xsb = H1[m2];
            const short* hsb = H2[(it + 1) & 1];
            A2[0] = *(const half8*)&xsb[(1 + kg) * GS + b * 8];
            A2[1] = *(const half8*)&xsb[(5 + kg) * GS + b * 8];
            A2[2] = *(const half8*)&hsb[(1 + kg) * GS + b * 8];
            A2[3] = *(const half8*)&hsb[(5 + kg) * GS + b * 8];
        }

        f32x4 a1 = (f32x4){0.0f, 0.0f, 0.0f, 0.0f};
        f32x4 a2 = (f32x4){0.0f, 0.0f, 0.0f, 0.0f};
        #pragma unroll
        for (int ks = 0; ks < 4; ++ks) {
            if (d1) a1 = __builtin_amdgcn_mfma_f32_16x16x32_f16(W1[0][ks], A1[ks], a1, 0, 0, 0);
            if (d2) a2 = __builtin_amdgcn_mfma_f32_16x16x32_f16(W2[0][ks], A2[ks], a2, 0, 0, 0);
        }

        const int n = 48 + kg;                    // valid kg<2
        if (d1 && kg < 2) {
            float h = cell_upd(a1, c1);
            H1[m1][(1 + (n >> 3)) * GS + b * 8 + (n & 7)] = (short)f2h(h);
        }
        if (d2 && kg < 2) {
            float h = cell_upd(a2, c2);
            H2[it & 1][(1 + (n >> 3)) * GS + b * 8 + (n & 7)] = (short)f2h(h);
            if (t2 == T_STEPS - 1) hfp[b * 56 + n] = h;
        }
        BAR();
        int tmp = m2; m2 = m1; m1 = m0; m0 = tmp;
    }
}

__global__ __launch_bounds__(NTHR) void lstm_fused(
    const float* __restrict__ xf,
    const float* w_ih0, const float* w_hh0, const float* b_ih0, const float* b_hh0,
    const float* w_ih1, const float* w_hh1, const float* b_ih1, const float* b_hh1,
    const float* w_ih2, const float* w_hh2, const float* b_ih2, const float* b_hh2,
    const float* __restrict__ w_fc, const float* __restrict__ b_fc,
    float* __restrict__ out)
{
    __shared__ __align__(16) short H0[2][BUFR];
    __shared__ __align__(16) short H1[3][BUFR];
    __shared__ __align__(16) short H2[2][BUFR];
    __shared__ __align__(16) float hf[16 * 56];

    const int tid  = threadIdx.x;
    const int lane = tid & 63;
    const int wid  = tid >> 6;
    const int b0   = blockIdx.x * 16;

    for (int i = tid; i < 2 * BUFR; i += NTHR) { ((short*)H0)[i] = 0; ((short*)H2)[i] = 0; }
    for (int i = tid; i < 3 * BUFR; i += NTHR) ((short*)H1)[i] = 0;
    __syncthreads();

    // act==1.0 bias columns (g7 p2 = unit slot 50), fp16 0x3C00:
    // H0 both bufs (serves L0 bias@58 AND L1 bias@50-shifted);
    // H1 all 3 (serves L2 bias). x(0) -> H0[0].g0.
    if (tid < 80) {
        int bufi = tid >> 4, b = tid & 15;
        short* bp = (bufi < 2) ? H0[bufi] : H1[bufi - 2];
        bp[7 * GS + b * 8 + 2] = (short)0x3C00;
    }
    if (tid < 16) {
        int b = tid;
        #pragma unroll
        for (int j = 0; j < 8; ++j) {
            float v = xf[((size_t)(b0 + b) * T_STEPS + 0) * 8 + j];
            H0[0][b * 8 + j] = (short)f2h(v);
        }
    }
    __syncthreads();

    if      (wid == 0)  role_l0<0, 5, false>(lane, b0, xf, w_ih0, w_hh0, b_ih0, b_hh0, H0);
    else if (wid == 1)  role_l0<5, 4, false>(lane, b0, xf, w_ih0, w_hh0, b_ih0, b_hh0, H0);
    else if (wid == 2)  role_l0<9, 4, true >(lane, b0, xf, w_ih0, w_hh0, b_ih0, b_hh0, H0);
    else if (wid == 3)  role_mid<0, false>(lane, w_ih1, w_hh1, b_ih1, b_hh1, H0, H1, H2, nullptr);
    else if (wid == 4)  role_mid<3, false>(lane, w_ih1, w_hh1, b_ih1, b_hh1, H0, H1, H2, nullptr);
    else if (wid == 5)  role_mid<6, false>(lane, w_ih1, w_hh1, b_ih1, b_hh1, H0, H1, H2, nullptr);
    else if (wid == 6)  role_mid<9, false>(lane, w_ih1, w_hh1, b_ih1, b_hh1, H0, H1, H2, nullptr);
    else if (wid == 7)  role_mid<0, true >(lane, w_ih2, w_hh2, b_ih2, b_hh2, H0, H1, H2, hf);
    else if (wid == 8)  role_mid<3, true >(lane, w_ih2, w_hh2, b_ih2, b_hh2, H0, H1, H2, hf);
    else if (wid == 9)  role_mid<6, true >(lane, w_ih2, w_hh2, b_ih2, b_hh2, H0, H1, H2, hf);
    else if (wid == 10) role_mid<9, true >(lane, w_ih2, w_hh2, b_ih2, b_hh2, H0, H1, H2, hf);
    else                role_orphan(lane,
                            w_ih1, w_hh1, b_ih1, b_hh1,
                            w_ih2, w_hh2, b_ih2, b_hh2,
                            H0, H1, H2, hf);

    __syncthreads();

    if (tid < 96) {
        int b = tid / 6, o = tid - b * 6;
        float a = b_fc[o];
        #pragma unroll
        for (int n = 0; n < 50; ++n)
            a = fmaf(w_fc[o * 50 + n], hf[b * 56 + n], a);
        out[(size_t)(b0 + b) * 6 + o] = a;
    }
}

extern "C" void kernel_launch(void* const* d_in, const int* in_sizes, int n_in,
                              void* d_out, int out_size, void* d_ws, size_t ws_size,
                              hipStream_t stream) {
    (void)in_sizes; (void)n_in; (void)d_ws; (void)ws_size; (void)out_size;

    const float* x     = (const float*)d_in[0];
    const float* w_ih0 = (const float*)d_in[1];
    const float* w_hh0 = (const float*)d_in[2];
    const float* b_ih0 = (const float*)d_in[3];
    const float* b_hh0 = (const float*)d_in[4];
    const float* w_ih1 = (const float*)d_in[5];
    const float* w_hh1 = (const float*)d_in[6];
    const float* b_ih1 = (const float*)d_in[7];
    const float* b_hh1 = (const float*)d_in[8];
    const float* w_ih2 = (const float*)d_in[9];
    const float* w_hh2 = (const float*)d_in[10];
    const float* b_ih2 = (const float*)d_in[11];
    const float* b_hh2 = (const float*)d_in[12];
    const float* w_fc  = (const float*)d_in[13];
    const float* b_fc  = (const float*)d_in[14];
    float* out = (float*)d_out;

    lstm_fused<<<dim3(BTOT / 16), dim3(NTHR), 0, stream>>>(
        x, w_ih0, w_hh0, b_ih0, b_hh0, w_ih1, w_hh1, b_ih1, b_hh1,
        w_ih2, w_hh2, b_ih2, b_hh2, w_fc, b_fc, out);
}